// Round 10
// baseline (358.334 us; speedup 1.0000x reference)
//
#include <hip/hip_runtime.h>

// ---------- helpers ----------
typedef __bf16 bf16x8 __attribute__((ext_vector_type(8)));
typedef float f32x16 __attribute__((ext_vector_type(16)));

__device__ __forceinline__ unsigned short f2bf(float f) {
  unsigned u = __float_as_uint(f);
  u += 0x7FFFu + ((u >> 16) & 1u);   // RNE
  return (unsigned short)(u >> 16);
}

__device__ __forceinline__ void gload_lds16(const void* g, void* l) {
  __builtin_amdgcn_global_load_lds((const __attribute__((address_space(1))) void*)g,
                                   (__attribute__((address_space(3))) void*)l,
                                   16, 0, 0);
}

#define NPTS 4096
#define LDX 576   // padded K for stage-1 GEMM1, divisible by BK=64

// ---------- batched weight transpose+convert: 6 weights in one launch
__global__ __launch_bounds__(256) void convw6_kernel(
    const float* w0, const float* w1, const float* w2,
    const float* r0, const float* r1, const float* r2,
    unsigned short* d0, unsigned short* d1, unsigned short* d2,
    unsigned short* e0, unsigned short* e1, unsigned short* e2) {
  int z = blockIdx.z;
  const float* src; unsigned short* dst; int Ksrc, Kpad, addI;
  switch (z) {
    case 0: src = w0; dst = d0; Ksrc = 524; Kpad = 576; addI = 0; break;
    case 1: src = w1; dst = d1; Ksrc = 513; Kpad = 576; addI = 0; break;
    case 2: src = w2; dst = d2; Ksrc = 513; Kpad = 576; addI = 0; break;
    case 3: src = r0; dst = e0; Ksrc = 512; Kpad = 512; addI = 1; break;
    case 4: src = r1; dst = e1; Ksrc = 512; Kpad = 512; addI = 1; break;
    default: src = r2; dst = e2; Ksrc = 512; Kpad = 512; addI = 1; break;
  }
  int k0 = blockIdx.x * 32;
  if (k0 >= Kpad) return;
  __shared__ float tile[32][33];
  int n0 = blockIdx.y * 32;
  int tx = threadIdx.x & 31, ty = threadIdx.x >> 5;  // 32 x 8
#pragma unroll
  for (int r = 0; r < 32; r += 8) {
    int k = k0 + ty + r, n = n0 + tx;
    tile[ty + r][tx] = (k < Ksrc) ? src[(size_t)k * 512 + n] : 0.f;
  }
  __syncthreads();
#pragma unroll
  for (int r = 0; r < 32; r += 8) {
    int n = n0 + ty + r, k = k0 + tx;
    float v = tile[tx][ty + r];
    if (addI && n == k) v += 1.0f;   // fold residual identity into Wr
    dst[(size_t)n * Kpad + k] = f2bf(v);
  }
}

// ---------- latent fp32 [M][512] -> X bf16 cols 0..511 (row stride LDX)
__global__ __launch_bounds__(256) void conv_latent_kernel(const float* __restrict__ latent,
                                                          unsigned short* __restrict__ X) {
  size_t idx = (size_t)blockIdx.x * 256 + threadIdx.x;  // over M*128 float4 groups
  size_t m = idx >> 7;
  int c4 = (int)(idx & 127) * 4;
  float4 v = *(const float4*)(latent + m * 512 + c4);
  ushort4 o;
  o.x = f2bf(v.x); o.y = f2bf(v.y); o.z = f2bf(v.z); o.w = f2bf(v.w);
  *(ushort4*)(X + m * LDX + c4) = o;
}

// ---------- KNN: nearest non-self neighbor + local covariance -> X cols 512..543
__device__ __forceinline__ void merge1(float& v, int& j, int mk) {
  float ov = __shfl_xor(v, mk); int oj = __shfl_xor(j, mk);
  bool take = (ov > v) || (ov == v && oj < j);   // tie -> lower index (reference top_k)
  v = take ? ov : v; j = take ? oj : j;
}

__global__ __launch_bounds__(512) void knn_kernel(const float* __restrict__ rp,
                                                  unsigned short* __restrict__ X) {
  __shared__ float4 P[NPTS];  // x,y,z,-|p|^2  (64 KB)
  int b = blockIdx.y;
  const float* base = rp + (size_t)b * 3 * NPTS;
  for (int j = threadIdx.x; j < NPTS; j += 512) {
    float x = base[j], y = base[NPTS + j], z = base[2 * NPTS + j];
    float xx = __fadd_rn(__fadd_rn(__fmul_rn(x, x), __fmul_rn(y, y)), __fmul_rn(z, z));
    P[j] = make_float4(x, y, z, -xx);
  }
  __syncthreads();
  int wave = threadIdx.x >> 6, lane = threadIdx.x & 63;
  int grp = lane >> 4, slice = lane & 15;
  int il0 = wave * 8 + grp * 2;          // this lane's two points: il0, il0+1
  int ia = blockIdx.x * 64 + il0;
  int ib = ia + 1;
  float4 pa = P[ia], pb = P[ib];
  float ax = 2.f * pa.x, ay = 2.f * pa.y, az = 2.f * pa.z;
  float bx = 2.f * pb.x, by = 2.f * pb.y, bz = 2.f * pb.z;
  float va = -3.4e38f, vb = -3.4e38f;
  int ta = 0, tb = 0;
  int sta = ((ia & 15) == slice) ? (ia >> 4) : -1;   // self-iteration to poison
  int stb = ((ib & 15) == slice) ? (ib >> 4) : -1;
  const float4* pp = P + slice;
#pragma unroll 8
  for (int t = 0; t < NPTS / 16; ++t) {
    float4 pj = pp[t * 16];
    float ea = __builtin_fmaf(ax, pj.x, __builtin_fmaf(ay, pj.y,
               __builtin_fmaf(az, pj.z, pj.w)));
    float eb = __builtin_fmaf(bx, pj.x, __builtin_fmaf(by, pj.y,
               __builtin_fmaf(bz, pj.z, pj.w)));
    ea = (t == sta) ? -3.4e38f : ea;
    eb = (t == stb) ? -3.4e38f : eb;
    bool ca = ea > va; va = ca ? ea : va; ta = ca ? t : ta;
    bool cb = eb > vb; vb = cb ? eb : vb; tb = cb ? t : tb;
  }
  int ja = ta * 16 + slice, jb = tb * 16 + slice;
#pragma unroll
  for (int mk = 1; mk <= 8; mk <<= 1) {
    merge1(va, ja, mk);
    merge1(vb, jb, mk);
  }
  if (slice == 0) {
#pragma unroll
    for (int p = 0; p < 2; ++p) {
      float4 pi = (p == 0) ? pa : pb;
      float4 p1 = P[(p == 0) ? ja : jb];   // nearest non-self neighbor
      size_t row = (size_t)b * NPTS + ia + p;
      unsigned short* xp = X + row * LDX + 512;
      float vals[12] = { pi.x, pi.y, pi.z,
                         pi.x * p1.x, pi.x * p1.y, pi.x * p1.z,
                         pi.y * p1.x, pi.y * p1.y, pi.y * p1.z,
                         pi.z * p1.x, pi.z * p1.y, pi.z * p1.z };
#pragma unroll
      for (int k = 0; k < 12; ++k) xp[k] = f2bf(vals[k]);
#pragma unroll
      for (int k = 12; k < 32; ++k) xp[k] = 0;   // cols 524..543 (zero weights there)
    }
  }
}

// ---------- GEMMs: R2 tile/fragment math + the guide's T3 minimum-2-phase loop:
// ONE barrier per K-tile (vs R2's two), vmcnt(0) drain moved AFTER the MFMA
// cluster (loads get the whole compute phase to land), setprio(1) around MFMA.
// Safety: compiler lgkm-waits retire all ds_reads before the last MFMA; explicit
// lgkmcnt(0)+vmcnt(0) before the barrier means at the barrier (i) every wave's
// next-buf stage landed, (ii) every wave's cur-buf reads are done -> restage-safe.
#define BM 256
#define BN 256
#define BK 64
#define GRP 520   // u16 per 8-row group (512 data + 8 pad)
#define MBLK 128  // M / BM
#define LDSU16 (2 * 64 * GRP)   // 2 buffers x (32 A-groups + 32 B-groups)

__global__ __launch_bounds__(512) void gemm_relu_kernel(
    const unsigned short* __restrict__ Xb, const unsigned short* __restrict__ Wt,
    const float* __restrict__ bias, unsigned short* __restrict__ H,
    int K, int ldx, int ldw,
    const float* __restrict__ std1, const float* __restrict__ std2,
    const float* __restrict__ w1row) {
  extern __shared__ unsigned short S[];   // [2][64*GRP]
  const int t = threadIdx.x;
  const int wave = t >> 6, lane = t & 63;
  const int flat = blockIdx.y * gridDim.x + blockIdx.x;
  const int m0 = (flat & (MBLK - 1)) * BM;   // co-panel blocks (f, f+128): same XCD
  const int n0 = (flat >> 7) * BN;
  const int wm = (wave >> 1) * 64;           // 4 m-waves
  const int wn = (wave & 1) * 128;           // 2 n-waves
  const int srow = lane >> 3;                // staging row within group (0..7)
  const int sslot = (lane & 7) ^ srow;       // permuted k-chunk this lane fetches
  const int l31 = lane & 31, hi = lane >> 5;
  const int w7 = l31 & 7, g2 = l31 >> 3;
  const unsigned short* Arow = Xb + (size_t)(m0 + srow) * ldx + sslot * 8;
  const unsigned short* Brow = Wt + (size_t)(n0 + srow) * ldw + sslot * 8;
  f32x16 acc[2][4] = {};
  const int nt = K / BK;
  auto STAGE = [&](int buf, int kt) {
#pragma unroll
    for (int r = 0; r < 4; ++r) {
      int g = wave + r * 8;                  // A groups 0..31
      gload_lds16(Arow + (size_t)g * 8 * ldx + kt, S + buf * (64 * GRP) + g * GRP);
    }
#pragma unroll
    for (int r = 0; r < 4; ++r) {
      int g = wave + r * 8;                  // B groups 0..31
      gload_lds16(Brow + (size_t)g * 8 * ldw + kt, S + buf * (64 * GRP) + (32 + g) * GRP);
    }
  };
  STAGE(0, 0);
  asm volatile("s_waitcnt vmcnt(0)" ::: "memory");
  __builtin_amdgcn_s_barrier();              // tile 0 landed for all waves
  for (int tt = 0; tt < nt; ++tt) {
    const int cur = tt & 1;
    const bool pf = (tt + 1 < nt);
    if (pf) STAGE(cur ^ 1, (tt + 1) * BK);   // issue next tile, no wait
    const unsigned short* Sa = S + cur * (64 * GRP);
    const unsigned short* Sb = Sa + 32 * GRP;
    __builtin_amdgcn_s_setprio(1);
#pragma unroll
    for (int ks = 0; ks < 4; ++ks) {
      int qx = (ks * 2 + hi) ^ w7;
      bf16x8 a[2], bb[4];
#pragma unroll
      for (int i = 0; i < 2; ++i)
        a[i] = *(const bf16x8*)(Sa + ((wm >> 3) + i * 4 + g2) * GRP + w7 * 64 + qx * 8);
#pragma unroll
      for (int j = 0; j < 4; ++j)
        bb[j] = *(const bf16x8*)(Sb + ((wn >> 3) + j * 4 + g2) * GRP + w7 * 64 + qx * 8);
#pragma unroll
      for (int i = 0; i < 2; ++i)
#pragma unroll
        for (int j = 0; j < 4; ++j)
          acc[i][j] = __builtin_amdgcn_mfma_f32_32x32x16_bf16(a[i], bb[j], acc[i][j], 0, 0, 0);
    }
    __builtin_amdgcn_s_setprio(0);
    if (pf) {
      asm volatile("s_waitcnt lgkmcnt(0)" ::: "memory");  // all cur reads retired
      asm volatile("s_waitcnt vmcnt(0)" ::: "memory");    // next tile landed (cheap: had MFMA time)
      __builtin_amdgcn_sched_barrier(0);
      __builtin_amdgcn_s_barrier();                        // single barrier per tile
    }
  }
  // rank-1 std fold (stages 2/3): acc += std[row] * w1row[col], in f32
  if (w1row) {
    float wv[4];
#pragma unroll
    for (int j = 0; j < 4; ++j) wv[j] = w1row[n0 + wn + j * 32 + l31];
#pragma unroll
    for (int i = 0; i < 2; ++i) {
#pragma unroll
      for (int rg = 0; rg < 16; ++rg) {
        int row = m0 + wm + i * 32 + (rg & 3) + 8 * (rg >> 2) + 4 * hi;
        float sv = std1[row];
        if (std2) sv += std2[row];
#pragma unroll
        for (int j = 0; j < 4; ++j) acc[i][j][rg] += sv * wv[j];
      }
    }
  }
  // epilogue: C/D layout col=lane&31, row=(reg&3)+8*(reg>>2)+4*(lane>>5)  [m74/m101]
#pragma unroll
  for (int j = 0; j < 4; ++j) {
    int col = n0 + wn + j * 32 + l31;
    float bv = bias[col];
#pragma unroll
    for (int i = 0; i < 2; ++i) {
#pragma unroll
      for (int rg = 0; rg < 16; ++rg) {
        int row = m0 + wm + i * 32 + (rg & 3) + 8 * (rg >> 2) + 4 * hi;
        float v = acc[i][j][rg] + bv;
        v = v > 0.f ? v : 0.f;
        H[(size_t)row * 512 + col] = f2bf(v);
      }
    }
  }
}

// ---------- GEMM2: h2 = relu(H1 @ (Wr+I) + br); so[row] += h2 . w2  (atomic)
__global__ __launch_bounds__(512) void gemm_res_kernel(
    const unsigned short* __restrict__ H1, const unsigned short* __restrict__ Wt,
    const float* __restrict__ br, const float* __restrict__ w2,
    float* __restrict__ so) {
  extern __shared__ unsigned short S[];
  const int t = threadIdx.x;
  const int wave = t >> 6, lane = t & 63;
  const int flat = blockIdx.y * gridDim.x + blockIdx.x;
  const int m0 = (flat & (MBLK - 1)) * BM;
  const int n0 = (flat >> 7) * BN;
  const int wm = (wave >> 1) * 64;
  const int wn = (wave & 1) * 128;
  const int srow = lane >> 3;
  const int sslot = (lane & 7) ^ srow;
  const int l31 = lane & 31, hi = lane >> 5;
  const int w7 = l31 & 7, g2 = l31 >> 3;
  const unsigned short* Arow = H1 + (size_t)(m0 + srow) * 512 + sslot * 8;
  const unsigned short* Brow = Wt + (size_t)(n0 + srow) * 512 + sslot * 8;
  f32x16 acc[2][4] = {};
  auto STAGE = [&](int buf, int kt) {
#pragma unroll
    for (int r = 0; r < 4; ++r) {
      int g = wave + r * 8;
      gload_lds16(Arow + (size_t)g * 8 * 512 + kt, S + buf * (64 * GRP) + g * GRP);
    }
#pragma unroll
    for (int r = 0; r < 4; ++r) {
      int g = wave + r * 8;
      gload_lds16(Brow + (size_t)g * 8 * 512 + kt, S + buf * (64 * GRP) + (32 + g) * GRP);
    }
  };
  STAGE(0, 0);
  asm volatile("s_waitcnt vmcnt(0)" ::: "memory");
  __builtin_amdgcn_s_barrier();
  const int nt = 512 / BK;
  for (int tt = 0; tt < nt; ++tt) {
    const int cur = tt & 1;
    const bool pf = (tt + 1 < nt);
    if (pf) STAGE(cur ^ 1, (tt + 1) * BK);
    const unsigned short* Sa = S + cur * (64 * GRP);
    const unsigned short* Sb = Sa + 32 * GRP;
    __builtin_amdgcn_s_setprio(1);
#pragma unroll
    for (int ks = 0; ks < 4; ++ks) {
      int qx = (ks * 2 + hi) ^ w7;
      bf16x8 a[2], bb[4];
#pragma unroll
      for (int i = 0; i < 2; ++i)
        a[i] = *(const bf16x8*)(Sa + ((wm >> 3) + i * 4 + g2) * GRP + w7 * 64 + qx * 8);
#pragma unroll
      for (int j = 0; j < 4; ++j)
        bb[j] = *(const bf16x8*)(Sb + ((wn >> 3) + j * 4 + g2) * GRP + w7 * 64 + qx * 8);
#pragma unroll
      for (int i = 0; i < 2; ++i)
#pragma unroll
        for (int j = 0; j < 4; ++j)
          acc[i][j] = __builtin_amdgcn_mfma_f32_32x32x16_bf16(a[i], bb[j], acc[i][j], 0, 0, 0);
    }
    __builtin_amdgcn_s_setprio(0);
    if (pf) {
      asm volatile("s_waitcnt lgkmcnt(0)" ::: "memory");
      asm volatile("s_waitcnt vmcnt(0)" ::: "memory");
      __builtin_amdgcn_sched_barrier(0);
      __builtin_amdgcn_s_barrier();
    }
  }
  float bv[4], wv[4];
#pragma unroll
  for (int j = 0; j < 4; ++j) {
    int col = n0 + wn + j * 32 + l31;
    bv[j] = br[col]; wv[j] = w2[col];
  }
#pragma unroll
  for (int i = 0; i < 2; ++i) {
#pragma unroll
    for (int rg = 0; rg < 16; ++rg) {
      float s = 0.f;
#pragma unroll
      for (int j = 0; j < 4; ++j) {
        float v = acc[i][j][rg] + bv[j];   // residual folded into Wr+I
        v = v > 0.f ? v : 0.f;
        s += v * wv[j];
      }
      s += __shfl_xor(s, 1); s += __shfl_xor(s, 2); s += __shfl_xor(s, 4);
      s += __shfl_xor(s, 8); s += __shfl_xor(s, 16);
      if (l31 == 0) {
        int row = m0 + wm + i * 32 + (rg & 3) + 8 * (rg >> 2) + 4 * hi;
        atomicAdd(&so[row], s);
      }
    }
  }
}

// ---------- small kernels ----------
// 3 stage accumulators so0/so1/so2, each pre-loaded with its b2 -> update kernels gone:
// std1 = so0; std2 = so0+so1; out = so0+so1+so2.   (proven in rounds 7 & 9)
__global__ __launch_bounds__(256) void init_so3_kernel(float* so0, float* so1, float* so2,
                                                       const float* b2_0, const float* b2_1,
                                                       const float* b2_2) {
  int m = blockIdx.x * 256 + threadIdx.x;
  so0[m] = b2_0[0];
  so1[m] = b2_1[0];
  so2[m] = b2_2[0];
}
__global__ __launch_bounds__(256) void finalize_kernel(float* out, const float* so0,
                                                       const float* so1, const float* so2) {
  int m = blockIdx.x * 256 + threadIdx.x;
  out[m] = so0[m] + so1[m] + so2[m];
}

extern "C" void kernel_launch(void* const* d_in, const int* in_sizes, int n_in,
                              void* d_out, int out_size, void* d_ws, size_t ws_size,
                              hipStream_t stream) {
  const int B = 8, N = NPTS, M = B * N;
  const float* latent = (const float*)d_in[0];
  const float* rp = (const float*)d_in[1];
  const float* w1[3] = {(const float*)d_in[2], (const float*)d_in[8], (const float*)d_in[14]};
  const float* b1[3] = {(const float*)d_in[3], (const float*)d_in[9], (const float*)d_in[15]};
  const float* wr[3] = {(const float*)d_in[4], (const float*)d_in[10], (const float*)d_in[16]};
  const float* br[3] = {(const float*)d_in[5], (const float*)d_in[11], (const float*)d_in[17]};
  const float* w2[3] = {(const float*)d_in[6], (const float*)d_in[12], (const float*)d_in[18]};
  const float* b2[3] = {(const float*)d_in[7], (const float*)d_in[13], (const float*)d_in[19]};

  char* ws = (char*)d_ws;
  auto carve = [&](size_t bytes) {
    char* p = ws;
    ws += (bytes + 255) & ~(size_t)255;
    return p;
  };
  unsigned short* X  = (unsigned short*)carve((size_t)M * LDX * 2);
  unsigned short* H1 = (unsigned short*)carve((size_t)M * 512 * 2);
  unsigned short* W1t[3], *Wrt[3];
  for (int s = 0; s < 3; ++s) W1t[s] = (unsigned short*)carve((size_t)512 * LDX * 2);
  for (int s = 0; s < 3; ++s) Wrt[s] = (unsigned short*)carve((size_t)512 * 512 * 2);
  float* so0 = (float*)carve((size_t)M * 4);
  float* so1 = (float*)carve((size_t)M * 4);
  float* so2 = (float*)carve((size_t)M * 4);

  const size_t ldsBytes = (size_t)LDSU16 * 2;   // 133,120 B

  convw6_kernel<<<dim3(LDX / 32, 16, 6), 256, 0, stream>>>(
      w1[0], w1[1], w1[2], wr[0], wr[1], wr[2],
      W1t[0], W1t[1], W1t[2], Wrt[0], Wrt[1], Wrt[2]);
  conv_latent_kernel<<<(M * 128) / 256, 256, 0, stream>>>(latent, X);
  knn_kernel<<<dim3(N / 64, B), 512, 0, stream>>>(rp, X);
  init_so3_kernel<<<M / 256, 256, 0, stream>>>(so0, so1, so2, b2[0], b2[1], b2[2]);

  float* soArr[3] = {so0, so1, so2};
  for (int s = 0; s < 3; ++s) {
    if (s == 0) {
      gemm_relu_kernel<<<dim3(512 / BN, M / BM), 512, ldsBytes, stream>>>(
          X, W1t[s], b1[s], H1, LDX, LDX, LDX, nullptr, nullptr, nullptr);
    } else {
      gemm_relu_kernel<<<dim3(512 / BN, M / BM), 512, ldsBytes, stream>>>(
          X, W1t[s], b1[s], H1, 512, LDX, LDX,
          so0, (s == 2) ? so1 : nullptr, w1[s] + (size_t)512 * 512);
    }
    gemm_res_kernel<<<dim3(512 / BN, M / BM), 512, ldsBytes, stream>>>(
        H1, Wrt[s], br[s], w2[s], soArr[s]);
  }
  finalize_kernel<<<M / 256, 256, 0, stream>>>((float*)d_out, so0, so1, so2);
}

// Round 11
// 324.610 us; speedup vs baseline: 1.1039x; 1.1039x over previous
//
#include <hip/hip_runtime.h>

// ---------- helpers ----------
typedef __bf16 bf16x8 __attribute__((ext_vector_type(8)));
typedef float f32x16 __attribute__((ext_vector_type(16)));

__device__ __forceinline__ unsigned short f2bf(float f) {
  unsigned u = __float_as_uint(f);
  u += 0x7FFFu + ((u >> 16) & 1u);   // RNE
  return (unsigned short)(u >> 16);
}

__device__ __forceinline__ void gload_lds16(const void* g, void* l) {
  __builtin_amdgcn_global_load_lds((const __attribute__((address_space(1))) void*)g,
                                   (__attribute__((address_space(3))) void*)l,
                                   16, 0, 0);
}

#define NPTS 4096
#define LDX 576   // padded K (shared by all stages; W rows 512..575 zero for s>=1)
#define LDH 1536  // Hpre row stride: 3 stages x 512
#define BM 256
#define BN 256
#define BK 64
#define GRP 520   // u16 per 8-row group (512 data + 8 pad)
#define MBLK 128  // M / BM
#define LDSU16 (2 * 64 * GRP)

// ---------- batched weight transpose+convert: 6 weights in one launch
// z=0: w1[0] [524][512] -> Wcat rows [0,512) cols 0..575
// z=1,2: w1[z] rows 0..511 ONLY (std row 512 excluded -> rank-1 at G2) -> Wcat slice
// z>=3: wr -> Wrt [512][512] with +I folded
__global__ __launch_bounds__(256) void convw6_kernel(
    const float* w0, const float* w1, const float* w2,
    const float* r0, const float* r1, const float* r2,
    unsigned short* d0, unsigned short* d1, unsigned short* d2,
    unsigned short* e0, unsigned short* e1, unsigned short* e2) {
  int z = blockIdx.z;
  const float* src; unsigned short* dst; int Ksrc, Kpad, addI;
  switch (z) {
    case 0: src = w0; dst = d0; Ksrc = 524; Kpad = 576; addI = 0; break;
    case 1: src = w1; dst = d1; Ksrc = 512; Kpad = 576; addI = 0; break;
    case 2: src = w2; dst = d2; Ksrc = 512; Kpad = 576; addI = 0; break;
    case 3: src = r0; dst = e0; Ksrc = 512; Kpad = 512; addI = 1; break;
    case 4: src = r1; dst = e1; Ksrc = 512; Kpad = 512; addI = 1; break;
    default: src = r2; dst = e2; Ksrc = 512; Kpad = 512; addI = 1; break;
  }
  int k0 = blockIdx.x * 32;
  if (k0 >= Kpad) return;
  __shared__ float tile[32][33];
  int n0 = blockIdx.y * 32;
  int tx = threadIdx.x & 31, ty = threadIdx.x >> 5;  // 32 x 8
#pragma unroll
  for (int r = 0; r < 32; r += 8) {
    int k = k0 + ty + r, n = n0 + tx;
    tile[ty + r][tx] = (k < Ksrc) ? src[(size_t)k * 512 + n] : 0.f;
  }
  __syncthreads();
#pragma unroll
  for (int r = 0; r < 32; r += 8) {
    int n = n0 + ty + r, k = k0 + tx;
    float v = tile[tx][ty + r];
    if (addI && n == k) v += 1.0f;   // fold residual identity into Wr
    dst[(size_t)n * Kpad + k] = f2bf(v);
  }
}

// ---------- latent fp32 [M][512] -> X bf16 cols 0..511 (row stride LDX)
__global__ __launch_bounds__(256) void conv_latent_kernel(const float* __restrict__ latent,
                                                          unsigned short* __restrict__ X) {
  size_t idx = (size_t)blockIdx.x * 256 + threadIdx.x;  // over M*128 float4 groups
  size_t m = idx >> 7;
  int c4 = (int)(idx & 127) * 4;
  float4 v = *(const float4*)(latent + m * 512 + c4);
  ushort4 o;
  o.x = f2bf(v.x); o.y = f2bf(v.y); o.z = f2bf(v.z); o.w = f2bf(v.w);
  *(ushort4*)(X + m * LDX + c4) = o;
}

// ---------- KNN: nearest non-self neighbor + local covariance -> X cols 512..523,
// zeros through col 575 (no reliance on workspace memset).
__device__ __forceinline__ void merge1(float& v, int& j, int mk) {
  float ov = __shfl_xor(v, mk); int oj = __shfl_xor(j, mk);
  bool take = (ov > v) || (ov == v && oj < j);   // tie -> lower index (reference top_k)
  v = take ? ov : v; j = take ? oj : j;
}

__global__ __launch_bounds__(512) void knn_kernel(const float* __restrict__ rp,
                                                  unsigned short* __restrict__ X) {
  __shared__ float4 P[NPTS];  // x,y,z,-|p|^2  (64 KB)
  int b = blockIdx.y;
  const float* base = rp + (size_t)b * 3 * NPTS;
  for (int j = threadIdx.x; j < NPTS; j += 512) {
    float x = base[j], y = base[NPTS + j], z = base[2 * NPTS + j];
    float xx = __fadd_rn(__fadd_rn(__fmul_rn(x, x), __fmul_rn(y, y)), __fmul_rn(z, z));
    P[j] = make_float4(x, y, z, -xx);
  }
  __syncthreads();
  int wave = threadIdx.x >> 6, lane = threadIdx.x & 63;
  int grp = lane >> 4, slice = lane & 15;
  int il0 = wave * 8 + grp * 2;          // this lane's two points: il0, il0+1
  int ia = blockIdx.x * 64 + il0;
  int ib = ia + 1;
  float4 pa = P[ia], pb = P[ib];
  float ax = 2.f * pa.x, ay = 2.f * pa.y, az = 2.f * pa.z;
  float bx = 2.f * pb.x, by = 2.f * pb.y, bz = 2.f * pb.z;
  float va = -3.4e38f, vb = -3.4e38f;
  int ta = 0, tb = 0;
  int sta = ((ia & 15) == slice) ? (ia >> 4) : -1;   // self-iteration to poison
  int stb = ((ib & 15) == slice) ? (ib >> 4) : -1;
  const float4* pp = P + slice;
#pragma unroll 8
  for (int t = 0; t < NPTS / 16; ++t) {
    float4 pj = pp[t * 16];
    float ea = __builtin_fmaf(ax, pj.x, __builtin_fmaf(ay, pj.y,
               __builtin_fmaf(az, pj.z, pj.w)));
    float eb = __builtin_fmaf(bx, pj.x, __builtin_fmaf(by, pj.y,
               __builtin_fmaf(bz, pj.z, pj.w)));
    ea = (t == sta) ? -3.4e38f : ea;
    eb = (t == stb) ? -3.4e38f : eb;
    bool ca = ea > va; va = ca ? ea : va; ta = ca ? t : ta;
    bool cb = eb > vb; vb = cb ? eb : vb; tb = cb ? t : tb;
  }
  int ja = ta * 16 + slice, jb = tb * 16 + slice;
#pragma unroll
  for (int mk = 1; mk <= 8; mk <<= 1) {
    merge1(va, ja, mk);
    merge1(vb, jb, mk);
  }
  if (slice == 0) {
#pragma unroll
    for (int p = 0; p < 2; ++p) {
      float4 pi = (p == 0) ? pa : pb;
      float4 p1 = P[(p == 0) ? ja : jb];   // nearest non-self neighbor
      size_t row = (size_t)b * NPTS + ia + p;
      unsigned short* xp = X + row * LDX + 512;
      float vals[12] = { pi.x, pi.y, pi.z,
                         pi.x * p1.x, pi.x * p1.y, pi.x * p1.z,
                         pi.y * p1.x, pi.y * p1.y, pi.y * p1.z,
                         pi.z * p1.x, pi.z * p1.y, pi.z * p1.z };
#pragma unroll
      for (int k = 0; k < 12; ++k) xp[k] = f2bf(vals[k]);
#pragma unroll
      for (int k = 12; k < 64; ++k) xp[k] = 0;   // zero cols 524..575
    }
  }
}

// ---------- Batched GEMM1 (all 3 stages in one dispatch): Hpre = X @ Wcat^T + b1(stage)
// R10's proven 256^2 dbuf counted-vmcnt body. 768 blocks (1D): m = flat&127,
// n-generation = flat>>7 (0..5); generation 1 pulls X into L3 (37.7 MB << 256 MB),
// generations 2..6 hit L3 -> A HBM traffic ~X once instead of 3x.
// stage = n0>>9: stage 0 slice gets relu (no rank-1); stages 1/2 stored raw+bias.
__global__ __launch_bounds__(512) void gemm_big1(
    const unsigned short* __restrict__ Xb, const unsigned short* __restrict__ Wcat,
    const float* __restrict__ b1_0, const float* __restrict__ b1_1,
    const float* __restrict__ b1_2, unsigned short* __restrict__ H) {
  extern __shared__ unsigned short S[];   // [2][64*GRP]
  const int t = threadIdx.x;
  const int wave = t >> 6, lane = t & 63;
  const int flat = blockIdx.x;
  const int m0 = (flat & (MBLK - 1)) * BM;
  const int n0 = (flat >> 7) * BN;          // 0..1280
  const int stage = n0 >> 9;                // 0,0,1,1,2,2
  const float* bias = (stage == 0) ? b1_0 : ((stage == 1) ? b1_1 : b1_2);
  const int wm = (wave >> 1) * 64;
  const int wn = (wave & 1) * 128;
  const int srow = lane >> 3;
  const int sslot = (lane & 7) ^ srow;
  const int l31 = lane & 31, hi = lane >> 5;
  const int w7 = l31 & 7, g2 = l31 >> 3;
  const unsigned short* Arow = Xb + (size_t)(m0 + srow) * LDX + sslot * 8;
  const unsigned short* Brow = Wcat + (size_t)(n0 + srow) * LDX + sslot * 8;
  f32x16 acc[2][4] = {};
  const int nt = LDX / BK;
  auto STAGE = [&](int buf, int kt) {
#pragma unroll
    for (int r = 0; r < 4; ++r) {
      int g = wave + r * 8;
      gload_lds16(Arow + (size_t)g * 8 * LDX + kt, S + buf * (64 * GRP) + g * GRP);
    }
#pragma unroll
    for (int r = 0; r < 4; ++r) {
      int g = wave + r * 8;
      gload_lds16(Brow + (size_t)g * 8 * LDX + kt, S + buf * (64 * GRP) + (32 + g) * GRP);
    }
  };
  STAGE(0, 0);
  for (int tt = 0; tt < nt; ++tt) {
    const int cur = tt & 1;
    if (tt + 1 < nt) {
      STAGE(cur ^ 1, (tt + 1) * BK);
      asm volatile("s_waitcnt vmcnt(8)" ::: "memory");
    } else {
      asm volatile("s_waitcnt vmcnt(0)" ::: "memory");
    }
    __builtin_amdgcn_s_barrier();
    asm volatile("" ::: "memory");
    const unsigned short* Sa = S + cur * (64 * GRP);
    const unsigned short* Sb = Sa + 32 * GRP;
#pragma unroll
    for (int ks = 0; ks < 4; ++ks) {
      int qx = (ks * 2 + hi) ^ w7;
      bf16x8 a[2], bb[4];
#pragma unroll
      for (int i = 0; i < 2; ++i)
        a[i] = *(const bf16x8*)(Sa + ((wm >> 3) + i * 4 + g2) * GRP + w7 * 64 + qx * 8);
#pragma unroll
      for (int j = 0; j < 4; ++j)
        bb[j] = *(const bf16x8*)(Sb + ((wn >> 3) + j * 4 + g2) * GRP + w7 * 64 + qx * 8);
#pragma unroll
      for (int i = 0; i < 2; ++i)
#pragma unroll
        for (int j = 0; j < 4; ++j)
          acc[i][j] = __builtin_amdgcn_mfma_f32_32x32x16_bf16(a[i], bb[j], acc[i][j], 0, 0, 0);
    }
    asm volatile("" ::: "memory");
    __builtin_amdgcn_sched_barrier(0);
    __builtin_amdgcn_s_barrier();
    asm volatile("" ::: "memory");
  }
  // epilogue: C/D layout col=lane&31, row=(reg&3)+8*(reg>>2)+4*(lane>>5)  [m74/m101]
#pragma unroll
  for (int j = 0; j < 4; ++j) {
    int col = n0 + wn + j * 32 + l31;
    float bv = bias[col & 511];
#pragma unroll
    for (int i = 0; i < 2; ++i) {
#pragma unroll
      for (int rg = 0; rg < 16; ++rg) {
        int row = m0 + wm + i * 32 + (rg & 3) + 8 * (rg >> 2) + 4 * hi;
        float v = acc[i][j][rg] + bv;
        if (stage == 0) v = v > 0.f ? v : 0.f;   // stage 0: no rank-1, relu now
        H[(size_t)row * LDH + col] = f2bf(v);
      }
    }
  }
}

// ---------- GEMM2 per stage: A = stage's Hpre slice. s=0: slice already relu'd ->
// pure gload_lds. s>=1: reg-stage + rank-1(std*w1row) + relu -> ds_write to the
// SAME linear slot gload_lds would fill (lane*16B within group). Single-buffer
// 66.5 KB static LDS -> 2 blocks/CU; plain __syncthreads (mixed-type queue safe).
// h2 = relu(h1 @ (Wr+I) + br); so[row] += h2 . w2  (atomic)
__global__ __launch_bounds__(512) void gemm_res2(
    const unsigned short* __restrict__ Hpre, int soff,
    const unsigned short* __restrict__ Wt,
    const float* __restrict__ br, const float* __restrict__ w2,
    float* __restrict__ so,
    const float* __restrict__ std1, const float* __restrict__ std2,
    const float* __restrict__ w1row) {
  __shared__ unsigned short As[32 * GRP];
  __shared__ unsigned short Bs[32 * GRP];
  const int t = threadIdx.x;
  const int wave = t >> 6, lane = t & 63;
  const int flat = blockIdx.x;
  const int m0 = (flat & (MBLK - 1)) * BM;
  const int n0 = (flat >> 7) * BN;          // 0 or 256
  const int wm = (wave >> 1) * 64;
  const int wn = (wave & 1) * 128;
  const int srow = lane >> 3;
  const int sslot = (lane & 7) ^ srow;
  const int l31 = lane & 31, hi = lane >> 5;
  const int w7 = l31 & 7, g2 = l31 >> 3;
  const unsigned short* Brow = Wt + (size_t)(n0 + srow) * 512 + sslot * 8;
  size_t grow[4]; float sr[4];
#pragma unroll
  for (int r = 0; r < 4; ++r) {
    int row = m0 + (wave + r * 8) * 8 + srow;
    grow[r] = (size_t)row * LDH + soff + sslot * 8;
    sr[r] = (std1 != nullptr) ? (std1[row] + (std2 ? std2[row] : 0.f)) : 0.f;
  }
  f32x16 acc[2][4] = {};
  for (int kt = 0; kt < 512; kt += BK) {
#pragma unroll
    for (int r = 0; r < 4; ++r) {
      int g = wave + r * 8;
      gload_lds16(Brow + (size_t)g * 8 * 512 + kt, Bs + g * GRP);
    }
    if (std1 == nullptr) {
      // stage 0: slice already relu'd -> direct global->LDS
#pragma unroll
      for (int r = 0; r < 4; ++r) {
        int g = wave + r * 8;
        gload_lds16(Hpre + grow[r] + kt, As + g * GRP);
      }
    } else {
      // stages 1/2: reg-stage + rank-1 + relu -> same linear slot
      float4 wlo = *(const float4*)(w1row + kt + sslot * 8);
      float4 whi = *(const float4*)(w1row + kt + sslot * 8 + 4);
      float wv[8] = {wlo.x, wlo.y, wlo.z, wlo.w, whi.x, whi.y, whi.z, whi.w};
#pragma unroll
      for (int r = 0; r < 4; ++r) {
        uint4 av = *(const uint4*)(Hpre + grow[r] + kt);
        unsigned uu[4] = {av.x, av.y, av.z, av.w};
        unsigned o[4];
#pragma unroll
        for (int q = 0; q < 4; ++q) {
          float f0 = __uint_as_float(uu[q] << 16);          // bf16 lo -> f32
          float f1 = __uint_as_float(uu[q] & 0xffff0000u);  // bf16 hi -> f32
          f0 = __builtin_fmaf(sr[r], wv[2 * q], f0);
          f1 = __builtin_fmaf(sr[r], wv[2 * q + 1], f1);
          f0 = fmaxf(f0, 0.f);
          f1 = fmaxf(f1, 0.f);
          o[q] = (unsigned)f2bf(f0) | ((unsigned)f2bf(f1) << 16);
        }
        *(uint4*)(As + (wave + r * 8) * GRP + lane * 8) = make_uint4(o[0], o[1], o[2], o[3]);
      }
    }
    __syncthreads();   // drains vmcnt + lgkm: A and B tiles ready
#pragma unroll
    for (int ks = 0; ks < 4; ++ks) {
      int qx = (ks * 2 + hi) ^ w7;
      bf16x8 a[2], bb[4];
#pragma unroll
      for (int i = 0; i < 2; ++i)
        a[i] = *(const bf16x8*)(As + ((wm >> 3) + i * 4 + g2) * GRP + w7 * 64 + qx * 8);
#pragma unroll
      for (int j = 0; j < 4; ++j)
        bb[j] = *(const bf16x8*)(Bs + ((wn >> 3) + j * 4 + g2) * GRP + w7 * 64 + qx * 8);
#pragma unroll
      for (int i = 0; i < 2; ++i)
#pragma unroll
        for (int j = 0; j < 4; ++j)
          acc[i][j] = __builtin_amdgcn_mfma_f32_32x32x16_bf16(a[i], bb[j], acc[i][j], 0, 0, 0);
    }
    __syncthreads();   // reads done -> restage-safe
  }
  float bv[4], wv[4];
#pragma unroll
  for (int j = 0; j < 4; ++j) {
    int col = n0 + wn + j * 32 + l31;
    bv[j] = br[col]; wv[j] = w2[col];
  }
#pragma unroll
  for (int i = 0; i < 2; ++i) {
#pragma unroll
    for (int rg = 0; rg < 16; ++rg) {
      float s = 0.f;
#pragma unroll
      for (int j = 0; j < 4; ++j) {
        float v = acc[i][j][rg] + bv[j];   // residual folded into Wr+I
        v = v > 0.f ? v : 0.f;
        s += v * wv[j];
      }
      s += __shfl_xor(s, 1); s += __shfl_xor(s, 2); s += __shfl_xor(s, 4);
      s += __shfl_xor(s, 8); s += __shfl_xor(s, 16);
      if (l31 == 0) {
        int row = m0 + wm + i * 32 + (rg & 3) + 8 * (rg >> 2) + 4 * hi;
        atomicAdd(&so[row], s);
      }
    }
  }
}

// ---------- small kernels ----------
__global__ __launch_bounds__(256) void init_so3_kernel(float* so0, float* so1, float* so2,
                                                       const float* b2_0, const float* b2_1,
                                                       const float* b2_2) {
  int m = blockIdx.x * 256 + threadIdx.x;
  so0[m] = b2_0[0];
  so1[m] = b2_1[0];
  so2[m] = b2_2[0];
}
__global__ __launch_bounds__(256) void finalize_kernel(float* out, const float* so0,
                                                       const float* so1, const float* so2) {
  int m = blockIdx.x * 256 + threadIdx.x;
  out[m] = so0[m] + so1[m] + so2[m];
}

extern "C" void kernel_launch(void* const* d_in, const int* in_sizes, int n_in,
                              void* d_out, int out_size, void* d_ws, size_t ws_size,
                              hipStream_t stream) {
  const int B = 8, N = NPTS, M = B * N;
  const float* latent = (const float*)d_in[0];
  const float* rp = (const float*)d_in[1];
  const float* w1[3] = {(const float*)d_in[2], (const float*)d_in[8], (const float*)d_in[14]};
  const float* b1[3] = {(const float*)d_in[3], (const float*)d_in[9], (const float*)d_in[15]};
  const float* wr[3] = {(const float*)d_in[4], (const float*)d_in[10], (const float*)d_in[16]};
  const float* br[3] = {(const float*)d_in[5], (const float*)d_in[11], (const float*)d_in[17]};
  const float* w2[3] = {(const float*)d_in[6], (const float*)d_in[12], (const float*)d_in[18]};
  const float* b2[3] = {(const float*)d_in[7], (const float*)d_in[13], (const float*)d_in[19]};

  char* ws = (char*)d_ws;
  auto carve = [&](size_t bytes) {
    char* p = ws;
    ws += (bytes + 255) & ~(size_t)255;
    return p;
  };
  unsigned short* X    = (unsigned short*)carve((size_t)M * LDX * 2);    // 37.7 MB
  unsigned short* Hpre = (unsigned short*)carve((size_t)M * LDH * 2);    // 100.7 MB
  unsigned short* Wcat = (unsigned short*)carve((size_t)1536 * LDX * 2); // 1.8 MB
  unsigned short* Wrt[3];
  for (int s = 0; s < 3; ++s) Wrt[s] = (unsigned short*)carve((size_t)512 * 512 * 2);
  float* so0 = (float*)carve((size_t)M * 4);
  float* so1 = (float*)carve((size_t)M * 4);
  float* so2 = (float*)carve((size_t)M * 4);
  // total ~142.5 MB (fill-kernel evidence: ws_size ~268 MB)

  const size_t ldsBig = (size_t)LDSU16 * 2;   // 133,120 B for gemm_big1

  convw6_kernel<<<dim3(LDX / 32, 16, 6), 256, 0, stream>>>(
      w1[0], w1[1], w1[2], wr[0], wr[1], wr[2],
      Wcat, Wcat + (size_t)512 * LDX, Wcat + (size_t)1024 * LDX,
      Wrt[0], Wrt[1], Wrt[2]);
  conv_latent_kernel<<<(M * 128) / 256, 256, 0, stream>>>(latent, X);
  knn_kernel<<<dim3(N / 64, B), 512, 0, stream>>>(rp, X);
  init_so3_kernel<<<M / 256, 256, 0, stream>>>(so0, so1, so2, b2[0], b2[1], b2[2]);

  // one batched GEMM1 for all 3 stages: 768 blocks (6 n-generations x 128 m)
  gemm_big1<<<dim3((M / BM) * (LDH / BN)), 512, ldsBig, stream>>>(
      X, Wcat, b1[0], b1[1], b1[2], Hpre);

  float* soArr[3] = {so0, so1, so2};
  for (int s = 0; s < 3; ++s) {
    gemm_res2<<<dim3((M / BM) * (512 / BN)), 512, 0, stream>>>(
        Hpre, s * 512, Wrt[s], br[s], w2[s], soArr[s],
        (s == 0) ? nullptr : so0,
        (s == 2) ? so1 : nullptr,
        (s == 0) ? nullptr : (w1[s] + (size_t)512 * 512));
  }
  finalize_kernel<<<M / 256, 256, 0, stream>>>((float*)d_out, so0, so1, so2);
}